// Round 4
// baseline (296.618 us; speedup 1.0000x reference)
//
#include <hip/hip_runtime.h>

// Problem constants: B=4, SEQ=4096, D=64, BS=32, V=512, R=128, P=33024
#define Bn   4
#define SEQn 4096
#define Dn   64
#define BSn  32
#define Vn   512
#define Rn   128
#define PPB  8256   // p's per batch = R*(R+1)/2

// ---------------- Prologue: embT[b][d][v] = emb[b][v][d]  (512 KB in ws)
// 32 blocks x 256 thr, 64v x 64d LDS tile each. ~2 us.
__global__ __launch_bounds__(256) void transpose_kernel(
    const float* __restrict__ emb, float* __restrict__ embT)
{
  __shared__ float tile[64][65];
  int b  = blockIdx.x >> 3;
  int v0 = (blockIdx.x & 7) * 64;
  int t  = threadIdx.x;
#pragma unroll
  for (int k = 0; k < 4; ++k) {
    int idx = t + 256 * k;          // 0..1023
    int v   = idx >> 4;             // 0..63
    int d4  = idx & 15;
    float4 x = ((const float4*)(emb + ((size_t)b * Vn + v0 + v) * Dn))[d4];
    tile[v][d4 * 4 + 0] = x.x;
    tile[v][d4 * 4 + 1] = x.y;
    tile[v][d4 * 4 + 2] = x.z;
    tile[v][d4 * 4 + 3] = x.w;
  }
  __syncthreads();
#pragma unroll
  for (int k = 0; k < 4; ++k) {
    int idx = t + 256 * k;
    int d   = idx >> 4;
    int j4  = idx & 15;
    float4 y;
    y.x = tile[j4 * 4 + 0][d];
    y.y = tile[j4 * 4 + 1][d];
    y.z = tile[j4 * 4 + 2][d];
    y.w = tile[j4 * 4 + 3][d];
    ((float4*)(embT + ((size_t)b * Dn + d) * Vn + v0))[j4] = y;
  }
}

// ---------------- Fused GEMM + gather, half-slab blocks.
// Block = (b, r, h): computes 16 rows x 512 v of scores for q-rows
// r*32+h*16.., gathers the h-half (128 slots) of each of the (r+1) p's.
// LDS = 32 KB slab + 4.25 KB q = 36.25 KB -> 4 blocks/CU, 32 waves/CU.
// GEMM: q from LDS (wave-uniform broadcast b128), emb from pre-transposed
// embT in global (coalesced float4, L2-resident) -> no emb staging, no
// LDS pressure; ~10.4 us of VALU per CU, hidden under neighbors' gathers.
// Block mapping: under XCD round-robin, CU c hosts x = {c, c+256, c+512,
// c+768}; qd = x>>8 -> r in {a, 63-a, 64+a, 127-a} sums to 258 p's per CU
// exactly -> perfect load balance.
#define QWS 68   // q LDS word stride (64+4, float4-aligned)

#define LOADI(R0, R1, R2, R3, itb)                                        \
  {                                                                       \
    int p0_ = ((itb) + 0) * 4 + sub, p1_ = ((itb) + 1) * 4 + sub;         \
    int p2_ = ((itb) + 2) * 4 + sub, p3_ = ((itb) + 3) * 4 + sub;         \
    R0 = info4[(base + (size_t)(p0_ <= r ? p0_ : 0)) * 256 + t];          \
    R1 = info4[(base + (size_t)(p1_ <= r ? p1_ : 0)) * 256 + t];          \
    R2 = info4[(base + (size_t)(p2_ <= r ? p2_ : 0)) * 256 + t];          \
    R3 = info4[(base + (size_t)(p3_ <= r ? p3_ : 0)) * 256 + t];          \
  }

#define PROC1(RV, pp)                                                     \
  if ((pp) <= r) {                                                        \
    float4 o_;                                                            \
    o_.x = slab[rowoff + RV.x];                                           \
    o_.y = slab[rowoff + RV.y];                                           \
    o_.z = slab[rowoff + RV.z];                                           \
    o_.w = slab[rowoff + RV.w];                                           \
    out4[(base + (size_t)(pp)) * 256 + t] = o_;                           \
  }

#define PROCI(R0, R1, R2, R3, itb)                                        \
  {                                                                       \
    PROC1(R0, ((itb) + 0) * 4 + sub);                                     \
    PROC1(R1, ((itb) + 1) * 4 + sub);                                     \
    PROC1(R2, ((itb) + 2) * 4 + sub);                                     \
    PROC1(R3, ((itb) + 3) * 4 + sub);                                     \
  }

// one k-step of the d-quad: E = embT[d0+k][v0..v0+3], C = component k of Q
#define FMAK(C)                                                           \
  Ac0.x += Q0.C * E.x; Ac0.y += Q0.C * E.y;                               \
  Ac0.z += Q0.C * E.z; Ac0.w += Q0.C * E.w;                               \
  Ac1.x += Q1.C * E.x; Ac1.y += Q1.C * E.y;                               \
  Ac1.z += Q1.C * E.z; Ac1.w += Q1.C * E.w;                               \
  Ac2.x += Q2.C * E.x; Ac2.y += Q2.C * E.y;                               \
  Ac2.z += Q2.C * E.z; Ac2.w += Q2.C * E.w;                               \
  Ac3.x += Q3.C * E.x; Ac3.y += Q3.C * E.y;                               \
  Ac3.z += Q3.C * E.z; Ac3.w += Q3.C * E.w;

__global__ __launch_bounds__(512, 8) void fused_kernel(
    const float* __restrict__ q, const float* __restrict__ embT,
    const int* __restrict__ info, float* __restrict__ out)
{
  __shared__ float sq[16 * QWS];     // 4.25 KB [row][d]
  __shared__ float slab[16 * Vn];    // 32 KB   [i][v]

  const int x  = blockIdx.x;         // 0..1023
  const int b  = x & 3;
  const int u  = (x >> 2) & 63;
  const int qd = x >> 8;             // 0..3
  const int h  = u & 1;
  const int a  = u >> 1;             // 0..31
  const int r  = (qd == 0) ? a : (qd == 1) ? (63 - a)
               : (qd == 2) ? (64 + a) : (127 - a);

  const size_t base = (size_t)b * PPB + (((size_t)r * (r + 1)) >> 1);
  const int tid = threadIdx.x;

  // ---- stage q rows [r*32 + h*16, +16): 256 float4
  if (tid < 256) {
    const float4* qs4 = (const float4*)(q +
        ((size_t)b * SEQn + (size_t)r * BSn + (size_t)h * 16) * Dn);
    float4 v = qs4[tid];
    ((float4*)sq)[(tid >> 4) * (QWS / 4) + (tid & 15)] = v;
  }
  __syncthreads();

  // ---- GEMM: thread = (ig = tid>>7 -> rows ig*4.., v0 = (tid&127)*4)
  {
    const int ig = tid >> 7;             // wave-uniform
    const int v0 = (tid & 127) * 4;
    const float* qb    = sq + (ig * 4) * QWS;
    const float* ebase = embT + (size_t)b * Dn * Vn + v0;

    float4 Ac0 = {0,0,0,0}, Ac1 = {0,0,0,0}, Ac2 = {0,0,0,0}, Ac3 = {0,0,0,0};
#pragma unroll
    for (int d0 = 0; d0 < Dn; d0 += 4) {
      float4 Q0 = *(const float4*)(qb + d0);
      float4 Q1 = *(const float4*)(qb + QWS + d0);
      float4 Q2 = *(const float4*)(qb + 2 * QWS + d0);
      float4 Q3 = *(const float4*)(qb + 3 * QWS + d0);
      float4 E;
      E = *(const float4*)(ebase + (d0 + 0) * Vn);  FMAK(x)
      E = *(const float4*)(ebase + (d0 + 1) * Vn);  FMAK(y)
      E = *(const float4*)(ebase + (d0 + 2) * Vn);  FMAK(z)
      E = *(const float4*)(ebase + (d0 + 3) * Vn);  FMAK(w)
    }
    float* sb = slab + (ig * 4) * Vn + v0;
    *(float4*)(sb)          = Ac0;
    *(float4*)(sb + Vn)     = Ac1;
    *(float4*)(sb + 2 * Vn) = Ac2;
    *(float4*)(sb + 3 * Vn) = Ac3;
  }

  // ---- gather mapping
  const int sub    = tid >> 7;           // which p of the quad (0..3)
  const int t7     = tid & 127;          // slot within the half
  const int t      = h * 128 + t7;       // slot within the full p
  const int rowoff = (t7 >> 3) << 9;     // local slab row * 512

  const int4* info4 = (const int4*)info;
  float4*     out4  = (float4*)out;
  const int   NIT   = (r + 4) >> 2;      // groups of 4 p's

  // first info batch issued before the barrier (in flight during drain)
  int4 ivA0, ivA1, ivA2, ivA3;
  LOADI(ivA0, ivA1, ivA2, ivA3, 0);
  __syncthreads();   // slab complete

  for (int it0 = 0; it0 < NIT; it0 += 8) {
    int4 ivB0, ivB1, ivB2, ivB3;
    if (it0 + 4 < NIT) LOADI(ivB0, ivB1, ivB2, ivB3, it0 + 4);
    PROCI(ivA0, ivA1, ivA2, ivA3, it0);
    if (it0 + 8 < NIT) LOADI(ivA0, ivA1, ivA2, ivA3, it0 + 8);
    if (it0 + 4 < NIT) PROCI(ivB0, ivB1, ivB2, ivB3, it0 + 4);
  }
}

extern "C" void kernel_launch(void* const* d_in, const int* in_sizes, int n_in,
                              void* d_out, int out_size, void* d_ws, size_t ws_size,
                              hipStream_t stream) {
  const float* q    = (const float*)d_in[0];
  const float* emb  = (const float*)d_in[1];
  const int*   info = (const int*)d_in[2];
  // d_in[3]/d_in[4] (idxs_batch/idxs_row) derivable from tril structure.
  float* out  = (float*)d_out;
  float* embT = (float*)d_ws;   // 512 KB

  transpose_kernel<<<32, 256, 0, stream>>>(emb, embT);
  fused_kernel<<<1024, 512, 0, stream>>>(q, embT, info, out);
}

// Round 6
// 286.848 us; speedup vs baseline: 1.0341x; 1.0341x over previous
//
#include <hip/hip_runtime.h>

// Problem constants: B=4, SEQ=4096, D=64, BS=32, V=512, R=128, P=33024
#define Bn   4
#define SEQn 4096
#define Dn   64
#define BSn  32
#define Vn   512
#define Rn   128
#define PPB  8256   // p's per batch = R*(R+1)/2

// native clang vector types (nontemporal builtins reject HIP_vector_type)
typedef int   nint4   __attribute__((ext_vector_type(4)));
typedef float nfloat4 __attribute__((ext_vector_type(4)));

// ---------------- Phase 1: scores[b][m][v] = sum_d q[b][m][d] * emb[b][v][d]
// Block tile: 64 m x 128 v, 256 threads, per-thread 8m x 4v register tile.
#define TM   64
#define TVb  128
#define QP   68    // q LDS leading dim  (64+4: keeps b128 16B-aligned)
#define EP   132   // emb LDS leading dim (128+4)

__global__ __launch_bounds__(256) void scores_kernel(
    const float* __restrict__ q, const float* __restrict__ emb,
    float* __restrict__ scores)
{
  __shared__ float sq[Dn * QP];   // [d][m]
  __shared__ float se[Dn * EP];   // [d][v]

  int bx   = blockIdx.x;
  int vblk = bx & 3;            // V/TVb = 4
  int bblk = (bx >> 2) & 3;     // B = 4
  int mblk = bx >> 4;           // SEQ/TM = 64
  int m0 = mblk * TM;
  int v0 = vblk * TVb;

  const float* qbase = q   + ((size_t)bblk * SEQn + m0) * Dn;
  const float* ebase = emb + ((size_t)bblk * Vn   + v0) * Dn;

  int t = threadIdx.x;
  for (int idx = t; idx < TM * Dn / 4; idx += 256) {
    int e = idx * 4;
    int m = e >> 6;
    int d = e & 63;
    float4 x = *(const float4*)(qbase + (size_t)m * Dn + d);
    sq[(d + 0) * QP + m] = x.x;
    sq[(d + 1) * QP + m] = x.y;
    sq[(d + 2) * QP + m] = x.z;
    sq[(d + 3) * QP + m] = x.w;
  }
  for (int idx = t; idx < TVb * Dn / 4; idx += 256) {
    int e = idx * 4;
    int v = e >> 6;
    int d = e & 63;
    float4 x = *(const float4*)(ebase + (size_t)v * Dn + d);
    se[(d + 0) * EP + v] = x.x;
    se[(d + 1) * EP + v] = x.y;
    se[(d + 2) * EP + v] = x.z;
    se[(d + 3) * EP + v] = x.w;
  }
  __syncthreads();

  int tx = t & 31;
  int ty = t >> 5;
  int ml = ty * 8;
  int vl = tx * 4;

  float acc[8][4];
#pragma unroll
  for (int r = 0; r < 8; ++r)
#pragma unroll
    for (int k = 0; k < 4; ++k) acc[r][k] = 0.0f;

#pragma unroll 4
  for (int d = 0; d < Dn; ++d) {
    float4 qa = *(const float4*)&sq[d * QP + ml];
    float4 qb = *(const float4*)&sq[d * QP + ml + 4];
    float4 ev = *(const float4*)&se[d * EP + vl];
    float qr[8] = {qa.x, qa.y, qa.z, qa.w, qb.x, qb.y, qb.z, qb.w};
    float ek[4] = {ev.x, ev.y, ev.z, ev.w};
#pragma unroll
    for (int r = 0; r < 8; ++r)
#pragma unroll
      for (int k = 0; k < 4; ++k) acc[r][k] += qr[r] * ek[k];
  }

  float* obase = scores + ((size_t)bblk * SEQn + m0) * Vn + v0;
#pragma unroll
  for (int r = 0; r < 8; ++r) {
    float4 st = {acc[r][0], acc[r][1], acc[r][2], acc[r][3]};
    *(float4*)(obase + (size_t)(ml + r) * Vn + vl) = st;
  }
}

// ---------------- Phase 2: gather via HALF-ROW LDS slab, 512-thread blocks
// Round-1 proven structure (84.5 us, byte-exact writes), plus:
//  - NONTEMPORAL out stores + info loads: both are touch-once streams
//    (135 MB each per launch); nt keeps them from thrashing L2 so the
//    slab re-reads and write-combining stay efficient.
//  - Deeper pipeline: BOTH info batches issued before the barrier, in the
//    latency shadow of the stage loads (stage global-loads first, info
//    prefetch next, LDS writes after) -> ~12KB/wave in flight during
//    staging instead of 4KB.
// 32 KB LDS + 512 thr -> 4 blocks/CU, 32 waves/CU.
#define GCHUNK 32

__global__ __launch_bounds__(512, 8) void gather_kernel(
    const float* __restrict__ scores, const int* __restrict__ info,
    float* __restrict__ out)
{
  __shared__ float slab[16 * Vn];   // 32 KB: 16 rows of the (b,r) slab

  int cid  = blockIdx.x;   // [0, 640) = (chunk ccid, half h) interleaved
  int b    = blockIdx.y;
  int h    = cid & 1;      // which 16-row half
  int ccid = cid >> 1;     // [0, 320)

  // group g covers rows 32g..32g+31, each with (g+1) chunks; start = 16g(g+1)
  int g = 0;
  while (16 * (g + 1) * (g + 2) <= ccid) ++g;
  int local = ccid - 16 * g * (g + 1);
  int rq    = local / (g + 1);
  int chunk = local - rq * (g + 1);
  int r     = 32 * g + rq;
  int np    = min(GCHUNK, (r + 1) - chunk * GCHUNK);
  size_t p0 = (size_t)b * PPB + ((size_t)r * (r + 1)) / 2 + (size_t)chunk * GCHUNK;

  int tid = threadIdx.x;
  int sub = tid >> 7;          // which p of the quad (0..3)
  int t7  = tid & 127;         // position within the half: i_local = t7>>3
  int t   = h * 128 + t7;      // position within the full p (0..255)
  int rowoff = (t7 >> 3) << 9; // local row * 512

  const nint4* info4 = (const nint4*)info;
  nfloat4*     out4  = (nfloat4*)out;

  // ---- stage loads issued FIRST (they gate the barrier) ----
  const float4* src = (const float4*)(scores +
      ((size_t)b * SEQn + (size_t)r * BSn + (size_t)h * 16) * Vn);
  float4 s0 = src[tid];
  float4 s1 = src[tid + 512];
  float4 s2 = src[tid + 1024];
  float4 s3 = src[tid + 1536];

  // ---- both info batches prefetched in the stage-load latency shadow ----
  nint4 ivA[4];
#pragma unroll
  for (int k = 0; k < 4; ++k) {
    int pp = 4 * k + sub;
    size_t p = p0 + (pp < np ? pp : 0);   // clamp keeps loads in-bounds
    ivA[k] = __builtin_nontemporal_load(&info4[p * 256 + t]);
  }
  nint4 ivB[4];
  if (np > 16) {
#pragma unroll
    for (int k = 0; k < 4; ++k) {
      int pp = 16 + 4 * k + sub;
      size_t p = p0 + (pp < np ? pp : 0);
      ivB[k] = __builtin_nontemporal_load(&info4[p * 256 + t]);
    }
  }

  // ---- LDS writes (each waits only on its own load) ----
  {
    float4* dst = (float4*)slab;
    dst[tid]        = s0;
    dst[tid + 512]  = s1;
    dst[tid + 1024] = s2;
    dst[tid + 1536] = s3;
  }
  __syncthreads();

#pragma unroll
  for (int k = 0; k < 4; ++k) {
    int pp = 4 * k + sub;
    if (pp < np) {
      nfloat4 o;
      o.x = slab[rowoff + ivA[k].x];
      o.y = slab[rowoff + ivA[k].y];
      o.z = slab[rowoff + ivA[k].z];
      o.w = slab[rowoff + ivA[k].w];
      __builtin_nontemporal_store(o, &out4[(p0 + pp) * 256 + t]);
    }
  }

  if (np > 16) {
#pragma unroll
    for (int k = 0; k < 4; ++k) {
      int pp = 16 + 4 * k + sub;
      if (pp < np) {
        nfloat4 o;
        o.x = slab[rowoff + ivB[k].x];
        o.y = slab[rowoff + ivB[k].y];
        o.z = slab[rowoff + ivB[k].z];
        o.w = slab[rowoff + ivB[k].w];
        __builtin_nontemporal_store(o, &out4[(p0 + pp) * 256 + t]);
      }
    }
  }
}

extern "C" void kernel_launch(void* const* d_in, const int* in_sizes, int n_in,
                              void* d_out, int out_size, void* d_ws, size_t ws_size,
                              hipStream_t stream) {
  const float* q    = (const float*)d_in[0];
  const float* emb  = (const float*)d_in[1];
  const int*   info = (const int*)d_in[2];
  // d_in[3]/d_in[4] (idxs_batch/idxs_row) derivable from tril structure.

  float* scores = (float*)d_ws;   // B*SEQ*V*4 = 32 MiB
  float* out    = (float*)d_out;

  int gemm_blocks = (SEQn / TM) * Bn * (Vn / TVb);   // 1024
  scores_kernel<<<gemm_blocks, 256, 0, stream>>>(q, emb, scores);

  dim3 ggrid(640, Bn);   // 320 chunks x 2 half-row blocks per batch
  gather_kernel<<<ggrid, 512, 0, stream>>>(scores, info, out);
}

// Round 7
// 269.468 us; speedup vs baseline: 1.1008x; 1.0645x over previous
//
#include <hip/hip_runtime.h>

// Problem constants: B=4, SEQ=4096, D=64, BS=32, V=512, R=128, P=33024
#define Bn   4
#define SEQn 4096
#define Dn   64
#define BSn  32
#define Vn   512
#define Rn   128
#define PPB  8256   // p's per batch = R*(R+1)/2

// ---------------- Phase 1: scores[b][m][v] = sum_d q[b][m][d] * emb[b][v][d]
// 128m x 128v block tile, 256 threads, 8x8 per-thread register tile.
// Per d-step: 4 ds_read_b128 -> 64 FMA per thread (vs 3:32 before) =
// 2.7x better FMA:LDS ratio; LDS 66 KB -> 2 blocks/CU.
#define TM   128
#define TVb  128
#define LP   132   // LDS leading dim for both tiles (128+4, 16B-aligned rows)

__global__ __launch_bounds__(256) void scores_kernel(
    const float* __restrict__ q, const float* __restrict__ emb,
    float* __restrict__ scores)
{
  __shared__ float sq[Dn * LP];   // [d][m] 64 x 132 = 33 KB
  __shared__ float se[Dn * LP];   // [d][v] 64 x 132 = 33 KB

  int bx   = blockIdx.x;
  int vblk = bx & 3;            // V/TVb = 4
  int bblk = (bx >> 2) & 3;     // B = 4
  int mblk = bx >> 4;           // SEQ/TM = 32
  int m0 = mblk * TM;
  int v0 = vblk * TVb;

  const float* qbase = q   + ((size_t)bblk * SEQn + m0) * Dn;
  const float* ebase = emb + ((size_t)bblk * Vn   + v0) * Dn;

  int t = threadIdx.x;
#pragma unroll
  for (int it = 0; it < TM * Dn / 4 / 256; ++it) {   // 8 iters
    int idx = t + it * 256;
    int e = idx * 4;
    int m = e >> 6;
    int d = e & 63;
    float4 x = *(const float4*)(qbase + (size_t)m * Dn + d);
    sq[(d + 0) * LP + m] = x.x;
    sq[(d + 1) * LP + m] = x.y;
    sq[(d + 2) * LP + m] = x.z;
    sq[(d + 3) * LP + m] = x.w;
  }
#pragma unroll
  for (int it = 0; it < TVb * Dn / 4 / 256; ++it) {  // 8 iters
    int idx = t + it * 256;
    int e = idx * 4;
    int v = e >> 6;
    int d = e & 63;
    float4 x = *(const float4*)(ebase + (size_t)v * Dn + d);
    se[(d + 0) * LP + v] = x.x;
    se[(d + 1) * LP + v] = x.y;
    se[(d + 2) * LP + v] = x.z;
    se[(d + 3) * LP + v] = x.w;
  }
  __syncthreads();

  int tx = t & 15;              // 16 v-groups
  int ty = t >> 4;              // 16 m-groups
  int ml = ty * 8;
  int vl = tx * 8;

  float acc[8][8];
#pragma unroll
  for (int r = 0; r < 8; ++r)
#pragma unroll
    for (int k = 0; k < 8; ++k) acc[r][k] = 0.0f;

#pragma unroll 4
  for (int d = 0; d < Dn; ++d) {
    float4 qa = *(const float4*)&sq[d * LP + ml];      // wave-broadcast (ty-uniform)
    float4 qb = *(const float4*)&sq[d * LP + ml + 4];
    float4 ea = *(const float4*)&se[d * LP + vl];
    float4 eb = *(const float4*)&se[d * LP + vl + 4];
    float qr[8] = {qa.x, qa.y, qa.z, qa.w, qb.x, qb.y, qb.z, qb.w};
    float ek[8] = {ea.x, ea.y, ea.z, ea.w, eb.x, eb.y, eb.z, eb.w};
#pragma unroll
    for (int r = 0; r < 8; ++r)
#pragma unroll
      for (int k = 0; k < 8; ++k) acc[r][k] += qr[r] * ek[k];
  }

  float* obase = scores + ((size_t)bblk * SEQn + m0) * Vn + v0;
#pragma unroll
  for (int r = 0; r < 8; ++r) {
    float4 s0 = {acc[r][0], acc[r][1], acc[r][2], acc[r][3]};
    float4 s1 = {acc[r][4], acc[r][5], acc[r][6], acc[r][7]};
    *(float4*)(obase + (size_t)(ml + r) * Vn + vl)     = s0;
    *(float4*)(obase + (size_t)(ml + r) * Vn + vl + 4) = s1;
  }
}

// ---------------- Phase 2: gather via HALF-ROW LDS slab, 512-thread blocks
// VERBATIM round-2 config (best measured: 83.0 us, WRITE byte-exact).
// p = b*8256 + r*(r+1)/2 + c,  c in [0, r]
// Block owns 16 of the 32 slab rows (32 KB LDS) and serves the matching
// half of each p's output; sibling block owns the other half.
// 32 KB LDS + 512 thr -> 4 blocks/CU -> 32 waves/CU.
#define GCHUNK 32

__global__ __launch_bounds__(512, 8) void gather_kernel(
    const float* __restrict__ scores, const int* __restrict__ info,
    float* __restrict__ out)
{
  __shared__ float slab[16 * Vn];   // 32 KB: 16 rows of the (b,r) slab

  int cid  = blockIdx.x;   // [0, 640) = (chunk ccid, half h) interleaved
  int b    = blockIdx.y;
  int h    = cid & 1;      // which 16-row half
  int ccid = cid >> 1;     // [0, 320)

  // group g covers rows 32g..32g+31, each with (g+1) chunks; start = 16g(g+1)
  int g = 0;
  while (16 * (g + 1) * (g + 2) <= ccid) ++g;
  int local = ccid - 16 * g * (g + 1);
  int rq    = local / (g + 1);
  int chunk = local - rq * (g + 1);
  int r     = 32 * g + rq;
  int np    = min(GCHUNK, (r + 1) - chunk * GCHUNK);
  size_t p0 = (size_t)b * PPB + ((size_t)r * (r + 1)) / 2 + (size_t)chunk * GCHUNK;

  int tid = threadIdx.x;
  int sub = tid >> 7;          // which p of the quad (0..3)
  int t7  = tid & 127;         // position within the half: i_local = t7>>3
  int t   = h * 128 + t7;      // position within the full p (0..255)
  int rowoff = (t7 >> 3) << 9; // local row * 512

  const int4* info4 = (const int4*)info;
  float4*     out4  = (float4*)out;

  // batch A info preload (pp = 0..15) — independent of slab, overlaps staging
  int4 ivA[4];
#pragma unroll
  for (int k = 0; k < 4; ++k) {
    int pp = 4 * k + sub;
    size_t p = p0 + (pp < np ? pp : 0);   // clamp keeps loads in-bounds
    ivA[k] = info4[p * 256 + t];
  }

  // stage 16 rows: r*32 + h*16 .. +15, all 512 v  (2048 float4, 4 iters)
  {
    const float4* src = (const float4*)(scores +
        ((size_t)b * SEQn + (size_t)r * BSn + (size_t)h * 16) * Vn);
    float4* dst = (float4*)slab;
#pragma unroll
    for (int k = 0; k < 4; ++k) dst[tid + 512 * k] = src[tid + 512 * k];
  }
  __syncthreads();

  // batch B info loads (pp = 16..31) issued immediately, hide under batch A
  int4 ivB[4];
  if (np > 16) {
#pragma unroll
    for (int k = 0; k < 4; ++k) {
      int pp = 16 + 4 * k + sub;
      size_t p = p0 + (pp < np ? pp : 0);
      ivB[k] = info4[p * 256 + t];
    }
  }

#pragma unroll
  for (int k = 0; k < 4; ++k) {
    int pp = 4 * k + sub;
    if (pp < np) {
      float4 o;
      o.x = slab[rowoff + ivA[k].x];
      o.y = slab[rowoff + ivA[k].y];
      o.z = slab[rowoff + ivA[k].z];
      o.w = slab[rowoff + ivA[k].w];
      out4[(p0 + pp) * 256 + t] = o;
    }
  }

  if (np > 16) {
#pragma unroll
    for (int k = 0; k < 4; ++k) {
      int pp = 16 + 4 * k + sub;
      if (pp < np) {
        float4 o;
        o.x = slab[rowoff + ivB[k].x];
        o.y = slab[rowoff + ivB[k].y];
        o.z = slab[rowoff + ivB[k].z];
        o.w = slab[rowoff + ivB[k].w];
        out4[(p0 + pp) * 256 + t] = o;
      }
    }
  }
}

extern "C" void kernel_launch(void* const* d_in, const int* in_sizes, int n_in,
                              void* d_out, int out_size, void* d_ws, size_t ws_size,
                              hipStream_t stream) {
  const float* q    = (const float*)d_in[0];
  const float* emb  = (const float*)d_in[1];
  const int*   info = (const int*)d_in[2];
  // d_in[3]/d_in[4] (idxs_batch/idxs_row) derivable from tril structure.

  float* scores = (float*)d_ws;   // B*SEQ*V*4 = 32 MiB
  float* out    = (float*)d_out;

  int gemm_blocks = (SEQn / TM) * Bn * (Vn / TVb);   // 512
  scores_kernel<<<gemm_blocks, 256, 0, stream>>>(q, emb, scores);

  dim3 ggrid(640, Bn);   // 320 chunks x 2 half-row blocks per batch
  gather_kernel<<<ggrid, 512, 0, stream>>>(scores, info, out);
}

// Round 9
// 261.091 us; speedup vs baseline: 1.1361x; 1.0321x over previous
//
#include <hip/hip_runtime.h>

// Problem constants: B=4, SEQ=4096, D=64, BS=32, V=512, R=128, P=33024
#define Bn   4
#define SEQn 4096
#define Dn   64
#define BSn  32
#define Vn   512
#define Rn   128
#define PPB  8256   // p's per batch = R*(R+1)/2

// ---------------- Prologue: embT[b][d][v] = emb[b][v][d]  (512 KB in ws)
__global__ __launch_bounds__(256) void transpose_kernel(
    const float* __restrict__ emb, float* __restrict__ embT)
{
  __shared__ float tile[64][65];
  int b  = blockIdx.x >> 3;
  int v0 = (blockIdx.x & 7) * 64;
  int t  = threadIdx.x;
#pragma unroll
  for (int k = 0; k < 4; ++k) {
    int idx = t + 256 * k;          // 0..1023
    int v   = idx >> 4;             // 0..63
    int d4  = idx & 15;
    float4 x = ((const float4*)(emb + ((size_t)b * Vn + v0 + v) * Dn))[d4];
    tile[v][d4 * 4 + 0] = x.x;
    tile[v][d4 * 4 + 1] = x.y;
    tile[v][d4 * 4 + 2] = x.z;
    tile[v][d4 * 4 + 3] = x.w;
  }
  __syncthreads();
#pragma unroll
  for (int k = 0; k < 4; ++k) {
    int idx = t + 256 * k;
    int d   = idx >> 4;
    int j4  = idx & 15;
    float4 y;
    y.x = tile[j4 * 4 + 0][d];
    y.y = tile[j4 * 4 + 1][d];
    y.z = tile[j4 * 4 + 2][d];
    y.w = tile[j4 * 4 + 3][d];
    ((float4*)(embT + ((size_t)b * Dn + d) * Vn + v0))[j4] = y;
  }
}

// ---------------- Fused GEMM + gather, half-slab blocks (round-3 retry,
// spill bugs fixed).
// Block = (b, r, h): computes 16 rows x 512 v of scores in LDS (q from
// LDS broadcast, embT from global/L2), then gathers the h-half (128
// slots) of each of the (r+1) p's of row r.
// FIXES vs round 3: __launch_bounds__(512,4) -> VGPR cap 128 (was 32:
// GEMM needs ~50 live regs -> scratch spills -> +88 MiB HBM write traffic);
// info prefetch moved AFTER the GEMM (no 16-reg liveness across it).
// LDS = 32 KB slab + 4.25 KB q = 36.25 KB.
// Quadrant mapping: CU c hosts x = {c, c+256, c+512, c+768} under
// round-robin; r in {a, 63-a, 64+a, 127-a} -> 258 p's per CU exactly.
#define QWS 68   // q LDS word stride (64+4, float4-aligned)

#define LOADI(R0, R1, R2, R3, itb)                                        \
  {                                                                       \
    int p0_ = ((itb) + 0) * 4 + sub, p1_ = ((itb) + 1) * 4 + sub;         \
    int p2_ = ((itb) + 2) * 4 + sub, p3_ = ((itb) + 3) * 4 + sub;         \
    R0 = info4[(base + (size_t)(p0_ <= r ? p0_ : 0)) * 256 + t];          \
    R1 = info4[(base + (size_t)(p1_ <= r ? p1_ : 0)) * 256 + t];          \
    R2 = info4[(base + (size_t)(p2_ <= r ? p2_ : 0)) * 256 + t];          \
    R3 = info4[(base + (size_t)(p3_ <= r ? p3_ : 0)) * 256 + t];          \
  }

#define PROC1(RV, pp)                                                     \
  if ((pp) <= r) {                                                        \
    float4 o_;                                                            \
    o_.x = slab[rowoff + RV.x];                                           \
    o_.y = slab[rowoff + RV.y];                                           \
    o_.z = slab[rowoff + RV.z];                                           \
    o_.w = slab[rowoff + RV.w];                                           \
    out4[(base + (size_t)(pp)) * 256 + t] = o_;                           \
  }

#define PROCI(R0, R1, R2, R3, itb)                                        \
  {                                                                       \
    PROC1(R0, ((itb) + 0) * 4 + sub);                                     \
    PROC1(R1, ((itb) + 1) * 4 + sub);                                     \
    PROC1(R2, ((itb) + 2) * 4 + sub);                                     \
    PROC1(R3, ((itb) + 3) * 4 + sub);                                     \
  }

// one k-step of the d-quad: E = embT[d0+k][v0..v0+3], C = component k of Q
#define FMAK(C)                                                           \
  Ac0.x += Q0.C * E.x; Ac0.y += Q0.C * E.y;                               \
  Ac0.z += Q0.C * E.z; Ac0.w += Q0.C * E.w;                               \
  Ac1.x += Q1.C * E.x; Ac1.y += Q1.C * E.y;                               \
  Ac1.z += Q1.C * E.z; Ac1.w += Q1.C * E.w;                               \
  Ac2.x += Q2.C * E.x; Ac2.y += Q2.C * E.y;                               \
  Ac2.z += Q2.C * E.z; Ac2.w += Q2.C * E.w;                               \
  Ac3.x += Q3.C * E.x; Ac3.y += Q3.C * E.y;                               \
  Ac3.z += Q3.C * E.z; Ac3.w += Q3.C * E.w;

__global__ __launch_bounds__(512, 4) void fused_kernel(
    const float* __restrict__ q, const float* __restrict__ embT,
    const int* __restrict__ info, float* __restrict__ out)
{
  __shared__ float sq[16 * QWS];     // 4.25 KB [row][d]
  __shared__ float slab[16 * Vn];    // 32 KB   [i][v]

  const int x  = blockIdx.x;         // 0..1023
  const int b  = x & 3;
  const int u  = (x >> 2) & 63;
  const int qd = x >> 8;             // 0..3
  const int h  = u & 1;
  const int a  = u >> 1;             // 0..31
  const int r  = (qd == 0) ? a : (qd == 1) ? (63 - a)
               : (qd == 2) ? (64 + a) : (127 - a);

  const size_t base = (size_t)b * PPB + (((size_t)r * (r + 1)) >> 1);
  const int tid = threadIdx.x;

  // ---- stage q rows [r*32 + h*16, +16): 256 float4
  if (tid < 256) {
    const float4* qs4 = (const float4*)(q +
        ((size_t)b * SEQn + (size_t)r * BSn + (size_t)h * 16) * Dn);
    float4 v = qs4[tid];
    ((float4*)sq)[(tid >> 4) * (QWS / 4) + (tid & 15)] = v;
  }
  __syncthreads();

  // ---- GEMM: thread = (ig = tid>>7 -> rows ig*4.., v0 = (tid&127)*4)
  {
    const int ig = tid >> 7;             // wave-uniform
    const int v0 = (tid & 127) * 4;
    const float* qb    = sq + (ig * 4) * QWS;
    const float* ebase = embT + (size_t)b * Dn * Vn + v0;

    float4 Ac0 = {0,0,0,0}, Ac1 = {0,0,0,0}, Ac2 = {0,0,0,0}, Ac3 = {0,0,0,0};
#pragma unroll
    for (int d0 = 0; d0 < Dn; d0 += 4) {
      float4 Q0 = *(const float4*)(qb + d0);
      float4 Q1 = *(const float4*)(qb + QWS + d0);
      float4 Q2 = *(const float4*)(qb + 2 * QWS + d0);
      float4 Q3 = *(const float4*)(qb + 3 * QWS + d0);
      float4 E;
      E = *(const float4*)(ebase + (d0 + 0) * Vn);  FMAK(x)
      E = *(const float4*)(ebase + (d0 + 1) * Vn);  FMAK(y)
      E = *(const float4*)(ebase + (d0 + 2) * Vn);  FMAK(z)
      E = *(const float4*)(ebase + (d0 + 3) * Vn);  FMAK(w)
    }
    float* sb = slab + (ig * 4) * Vn + v0;
    *(float4*)(sb)          = Ac0;
    *(float4*)(sb + Vn)     = Ac1;
    *(float4*)(sb + 2 * Vn) = Ac2;
    *(float4*)(sb + 3 * Vn) = Ac3;
  }

  // ---- gather mapping
  const int sub    = tid >> 7;           // which p of the quad (0..3)
  const int t7     = tid & 127;          // slot within the half
  const int t      = h * 128 + t7;       // slot within the full p
  const int rowoff = (t7 >> 3) << 9;     // local slab row * 512

  const int4* info4 = (const int4*)info;
  float4*     out4  = (float4*)out;
  const int   NIT   = (r + 4) >> 2;      // groups of 4 p's

  // info batch A issued AFTER the GEMM (acc regs dead), before the
  // barrier: loads fly during the barrier drain, no liveness across GEMM.
  int4 ivA0, ivA1, ivA2, ivA3;
  LOADI(ivA0, ivA1, ivA2, ivA3, 0);
  __syncthreads();   // slab complete

  for (int it0 = 0; it0 < NIT; it0 += 8) {
    int4 ivB0, ivB1, ivB2, ivB3;
    if (it0 + 4 < NIT) LOADI(ivB0, ivB1, ivB2, ivB3, it0 + 4);
    PROCI(ivA0, ivA1, ivA2, ivA3, it0);
    if (it0 + 8 < NIT) LOADI(ivA0, ivA1, ivA2, ivA3, it0 + 8);
    if (it0 + 4 < NIT) PROCI(ivB0, ivB1, ivB2, ivB3, it0 + 4);
  }
}

extern "C" void kernel_launch(void* const* d_in, const int* in_sizes, int n_in,
                              void* d_out, int out_size, void* d_ws, size_t ws_size,
                              hipStream_t stream) {
  const float* q    = (const float*)d_in[0];
  const float* emb  = (const float*)d_in[1];
  const int*   info = (const int*)d_in[2];
  // d_in[3]/d_in[4] (idxs_batch/idxs_row) derivable from tril structure.
  float* out  = (float*)d_out;
  float* embT = (float*)d_ws;   // 512 KB

  transpose_kernel<<<32, 256, 0, stream>>>(emb, embT);
  fused_kernel<<<1024, 512, 0, stream>>>(q, embT, info, out);
}